// Round 3
// baseline (284.428 us; speedup 1.0000x reference)
//
#include <hip/hip_runtime.h>
#include <hip/hip_fp16.h>

#define B_ 4
#define N_ 8192
#define D_ 4096
#define E_ 64
#define M_ (B_ * N_)          // 32768 tokens
#define NK 64                 // K chunks of 64

typedef _Float16 half8 __attribute__((ext_vector_type(8)));
typedef float f32x4 __attribute__((ext_vector_type(4)));

union H4 { _Float16 h[4]; uint2 u2; };

// ---------------------------------------------------------------------------
// w (fp32 [E][D]) -> w16 (f16 [E][D]) once; L2-resident thereafter.
// ---------------------------------------------------------------------------
__global__ __launch_bounds__(256) void convert_w(const float* __restrict__ w,
                                                 _Float16* __restrict__ w16) {
  const int i = (blockIdx.x * 256 + threadIdx.x) * 4;
  const float4 v = *(const float4*)&w[i];
  H4 h;
  h.h[0] = (_Float16)v.x; h.h[1] = (_Float16)v.y;
  h.h[2] = (_Float16)v.z; h.h[3] = (_Float16)v.w;
  *(uint2*)&w16[i] = h.u2;
}

// ---------------------------------------------------------------------------
// GEMM: gates = x @ w16^T, no LDS, no barriers. Each wave owns 16 rows x 64 cols.
// A-frags: direct fp32 loads + cvt; B-frags: direct f16 16B loads (L2).
// Epilogue: t0 = log(clamp(gate,1e-6)), col-sum partials -> slot0 atomics.
// ---------------------------------------------------------------------------
__global__ __launch_bounds__(256, 2) void gemm_log(const float* __restrict__ x,
                                                   const _Float16* __restrict__ w16,
                                                   float* __restrict__ t0,
                                                   float* __restrict__ slot0) {
  const int tid = threadIdx.x;
  const int lane = tid & 63;
  const int wv = tid >> 6;                 // 0..3
  const int l15 = lane & 15;
  const int lq = lane >> 4;                // 0..3
  const int row16 = (blockIdx.x * 4 + wv) * 16;   // wave's 16 output rows
  const int b = row16 >> 13;               // row16 / N_

  const float* xA = x + (size_t)(row16 + l15) * D_ + lq * 8;
  const _Float16* wB = w16 + (size_t)l15 * D_ + lq * 8;

  f32x4 acc[4] = {};                       // ni = 0..3 (cols ni*16+l15)

  struct Regs {
    float4 a0, a1, a2, a3;                 // 16 fp32 of A (k = 0..7, 32..39 per lane)
    half8 bfr[8];                          // [ni*2+ks]
  };
  Regs rA, rB;

#define LOADC(R, KC)                                                        \
  do {                                                                      \
    const int o_ = (KC) * 64;                                               \
    (R).a0 = *(const float4*)(xA + o_);                                     \
    (R).a1 = *(const float4*)(xA + o_ + 4);                                 \
    (R).a2 = *(const float4*)(xA + o_ + 32);                                \
    (R).a3 = *(const float4*)(xA + o_ + 36);                                \
    _Pragma("unroll")                                                       \
    for (int ni = 0; ni < 4; ++ni) {                                        \
      (R).bfr[ni * 2 + 0] = *(const half8*)(wB + (size_t)ni * 16 * D_ + o_);      \
      (R).bfr[ni * 2 + 1] = *(const half8*)(wB + (size_t)ni * 16 * D_ + o_ + 32); \
    }                                                                       \
  } while (0)

#define COMPC(R)                                                            \
  do {                                                                      \
    half8 af0, af1;                                                         \
    af0[0] = (_Float16)(R).a0.x; af0[1] = (_Float16)(R).a0.y;               \
    af0[2] = (_Float16)(R).a0.z; af0[3] = (_Float16)(R).a0.w;               \
    af0[4] = (_Float16)(R).a1.x; af0[5] = (_Float16)(R).a1.y;               \
    af0[6] = (_Float16)(R).a1.z; af0[7] = (_Float16)(R).a1.w;               \
    af1[0] = (_Float16)(R).a2.x; af1[1] = (_Float16)(R).a2.y;               \
    af1[2] = (_Float16)(R).a2.z; af1[3] = (_Float16)(R).a2.w;               \
    af1[4] = (_Float16)(R).a3.x; af1[5] = (_Float16)(R).a3.y;               \
    af1[6] = (_Float16)(R).a3.z; af1[7] = (_Float16)(R).a3.w;               \
    _Pragma("unroll")                                                       \
    for (int ni = 0; ni < 4; ++ni) {                                        \
      acc[ni] = __builtin_amdgcn_mfma_f32_16x16x32_f16(af0, (R).bfr[ni * 2 + 0], acc[ni], 0, 0, 0); \
      acc[ni] = __builtin_amdgcn_mfma_f32_16x16x32_f16(af1, (R).bfr[ni * 2 + 1], acc[ni], 0, 0, 0); \
    }                                                                       \
  } while (0)

  LOADC(rA, 0);
  for (int kc = 0; kc < NK; kc += 2) {
    LOADC(rB, kc + 1);
    COMPC(rA);
    if (kc + 2 < NK) LOADC(rA, kc + 2);
    COMPC(rB);
  }
#undef LOADC
#undef COMPC

  // epilogue: clamp, log -> t0, column sums -> slot0
  float lsum[4];
#pragma unroll
  for (int ni = 0; ni < 4; ++ni) {
    lsum[ni] = 0.f;
#pragma unroll
    for (int r = 0; r < 4; ++r) {
      const float v = fmaxf(acc[ni][r], 1e-6f);
      const int grow = row16 + lq * 4 + r;
      const int gcol = ni * 16 + l15;
      t0[(size_t)grow * E_ + gcol] = __logf(v);
      lsum[ni] += v;
    }
    float v = lsum[ni];
    v += __shfl_xor(v, 16);
    v += __shfl_xor(v, 32);
    if (lq == 0) atomicAdd(&slot0[b * E_ + ni * 16 + l15], v);
  }
}

// ---------------------------------------------------------------------------
// One Sinkhorn iteration (fused col+row pass):
//   C_it[e] = sum_j log(slots[j][b][e]); p = exp(t0 - C); s = row-sum(p);
//   last: out = p/s; else slots[it] += col-sum(p/s)
// ---------------------------------------------------------------------------
__global__ __launch_bounds__(256) void sinkhorn_iter(const float* __restrict__ t0,
                                                     float* __restrict__ slots,
                                                     float* __restrict__ out,
                                                     int it, int last) {
  const int tid = threadIdx.x;
  const int lane = tid & 63;
  const int wv = tid >> 6;
  const int b = blockIdx.x >> 8;
  const int chunk = blockIdx.x & 255;

  float C = __logf(slots[b * E_ + lane]);
  for (int j = 1; j < it; ++j) C += __logf(slots[j * (B_ * E_) + b * E_ + lane]);

  float colacc = 0.f;
  const int nbase = chunk * 32 + wv * 8;
#pragma unroll
  for (int i = 0; i < 8; ++i) {
    const int n = nbase + i;
    const float v = t0[((size_t)b * N_ + n) * E_ + lane];
    const float p = __expf(v - C);
    float s = p;
    s += __shfl_xor(s, 1);  s += __shfl_xor(s, 2);  s += __shfl_xor(s, 4);
    s += __shfl_xor(s, 8);  s += __shfl_xor(s, 16); s += __shfl_xor(s, 32);
    const float q = p / s;
    if (last) out[((size_t)b * N_ + n) * E_ + lane] = q;
    else      colacc += q;
  }
  if (!last) {
    __shared__ float wsum[4][64];
    wsum[wv][lane] = colacc;
    __syncthreads();
    if (tid < 64) {
      const float tot = wsum[0][tid] + wsum[1][tid] + wsum[2][tid] + wsum[3][tid];
      atomicAdd(&slots[it * (B_ * E_) + b * E_ + tid], tot);
    }
  }
}

// ---------------------------------------------------------------------------
extern "C" void kernel_launch(void* const* d_in, const int* in_sizes, int n_in,
                              void* d_out, int out_size, void* d_ws, size_t ws_size,
                              hipStream_t stream) {
  (void)in_sizes; (void)n_in; (void)out_size; (void)ws_size;
  const float* x = (const float*)d_in[0];
  const float* w = (const float*)d_in[1];
  float* out = (float*)d_out;                       // t0 lives here, final iter overwrites
  float* slots = (float*)d_ws;                      // [8][B_][E_] = 8 KiB
  _Float16* w16 = (_Float16*)((char*)d_ws + 8192);  // 512 KiB

  hipMemsetAsync(slots, 0, 8 * B_ * E_ * sizeof(float), stream);
  convert_w<<<(E_ * D_) / 1024, 256, 0, stream>>>(w, w16);
  gemm_log<<<M_ / 64, 256, 0, stream>>>(x, w16, out, slots);
  for (int it = 1; it <= 8; ++it)
    sinkhorn_iter<<<B_ * 256, 256, 0, stream>>>(out, slots, out, it, it == 8 ? 1 : 0);
}

// Round 4
// 264.026 us; speedup vs baseline: 1.0773x; 1.0773x over previous
//
#include <hip/hip_runtime.h>
#include <hip/hip_fp16.h>

#define B_ 4
#define N_ 8192
#define D_ 4096
#define E_ 64
#define M_ (B_ * N_)          // 32768 tokens
#define NK 64                 // 64 K-chunks of 64

typedef _Float16 half8 __attribute__((ext_vector_type(8)));
typedef float f32x4 __attribute__((ext_vector_type(4)));

union H4 { _Float16 h[4]; uint2 u2; };

// ---------------------------------------------------------------------------
// w (fp32 [E][D]) -> w16 (f16 [E][D]) once; L2-resident thereafter.
// ---------------------------------------------------------------------------
__global__ __launch_bounds__(256) void convert_w(const float* __restrict__ w,
                                                 _Float16* __restrict__ w16) {
  const int i = (blockIdx.x * 256 + threadIdx.x) * 4;
  const float4 v = *(const float4*)&w[i];
  H4 h;
  h.h[0] = (_Float16)v.x; h.h[1] = (_Float16)v.y;
  h.h[2] = (_Float16)v.z; h.h[3] = (_Float16)v.w;
  *(uint2*)&w16[i] = h.u2;
}

// ---------------------------------------------------------------------------
// GEMM: gates = x @ w16^T.
// A: fp32 via global_load_lds DMA (linear LDS dest, source-side XOR swizzle),
//    double-buffered, counted vmcnt(4) — loads span 2 iterations, never drained.
// B: f16 direct from L2-resident w16 into fragment registers.
// Epilogue: t0 = log(clamp(gate,1e-6)) -> d_out; col-sum partials -> slot0.
// ---------------------------------------------------------------------------
__global__ __launch_bounds__(256, 2) void gemm_log(const float* __restrict__ x,
                                                   const _Float16* __restrict__ w16,
                                                   float* __restrict__ t0,
                                                   float* __restrict__ slot0) {
  __shared__ float As[2][64 * 64];        // 2 x 16 KiB

  const int tid = threadIdx.x;
  const int lane = tid & 63;
  const int wv = tid >> 6;                // 0..3
  const int l15 = lane & 15;
  const int lq = lane >> 4;               // 0..3
  const int rowBase = blockIdx.x * 64;
  const int b = rowBase >> 13;            // / N_
  const int wm = wv * 16;                 // wave's 16 output rows

  const _Float16* wB = w16 + (size_t)l15 * D_ + lq * 8;

  // DMA staging geometry: call g stages rows [g*16, g*16+16); within a call,
  // wave wv stages rows g*16 + wv*4 + (lane>>4), 16B unit (lane&15).
  // LDS dest is LINEAR; the XOR swizzle (unit ^= row&15) is applied to the
  // per-lane GLOBAL source address (m173 pattern).
  const int srow = wv * 4 + (lane >> 4);  // row within a 16-row group
#define STAGE(KC, BUF)                                                         \
  do {                                                                         \
    _Pragma("unroll")                                                          \
    for (int g = 0; g < 4; ++g) {                                              \
      const int r_ = g * 16 + srow;                                            \
      const int u_ = (lane & 15) ^ (r_ & 15);                                  \
      const float* src_ = x + (size_t)(rowBase + r_) * D_ + (KC) * 64 + u_ * 4;\
      __builtin_amdgcn_global_load_lds(                                        \
          (const __attribute__((address_space(1))) void*)src_,                 \
          (__attribute__((address_space(3))) void*)&As[BUF][(g * 16 + wv * 4) * 64], \
          16, 0, 0);                                                           \
    }                                                                          \
  } while (0)

  f32x4 acc[4] = {};                      // ni: cols ni*16 + l15

  // prologue: chunks 0 and 1 in flight
  STAGE(0, 0);
  STAGE(1, 1);

  for (int kc = 0; kc < NK; ++kc) {
    const int cur = kc & 1;
    // wait for THIS chunk's 4 DMA ops (the 4 newer ones for kc+1 keep flying)
    if (kc < NK - 1) asm volatile("s_waitcnt vmcnt(4)" ::: "memory");
    else             asm volatile("s_waitcnt vmcnt(0)" ::: "memory");
    __builtin_amdgcn_s_barrier();

    // B fragments for this chunk (L2-resident; compiler manages their waits)
    half8 bfr[8];
#pragma unroll
    for (int ni = 0; ni < 4; ++ni) {
      bfr[ni * 2 + 0] = *(const half8*)(wB + (size_t)ni * 16 * D_ + kc * 64);
      bfr[ni * 2 + 1] = *(const half8*)(wB + (size_t)ni * 16 * D_ + kc * 64 + 32);
    }

    // A fragments from LDS (swizzled read), cvt fp32->f16, MFMA
    const int row = wm + l15;
    const int rm = row & 15;
#pragma unroll
    for (int ks = 0; ks < 2; ++ks) {
      const int v0 = ks * 8 + lq * 2;
      const f32x4 p0 = *(const f32x4*)&As[cur][row * 64 + ((v0 ^ rm) << 2)];
      const f32x4 p1 = *(const f32x4*)&As[cur][row * 64 + (((v0 + 1) ^ rm) << 2)];
      half8 af;
      af[0] = (_Float16)p0[0]; af[1] = (_Float16)p0[1];
      af[2] = (_Float16)p0[2]; af[3] = (_Float16)p0[3];
      af[4] = (_Float16)p1[0]; af[5] = (_Float16)p1[1];
      af[6] = (_Float16)p1[2]; af[7] = (_Float16)p1[3];
#pragma unroll
      for (int ni = 0; ni < 4; ++ni)
        acc[ni] = __builtin_amdgcn_mfma_f32_16x16x32_f16(af, bfr[ni * 2 + ks], acc[ni], 0, 0, 0);
    }

    // my LDS reads drained, then block-wide rendezvous: buffer cur is free
    asm volatile("s_waitcnt lgkmcnt(0)" ::: "memory");
    __builtin_amdgcn_s_barrier();

    // refill the just-freed buffer with chunk kc+2
    if (kc + 2 < NK) STAGE(kc + 2, cur);
  }
#undef STAGE

  // epilogue: clamp, log -> t0, column sums -> slot0
#pragma unroll
  for (int ni = 0; ni < 4; ++ni) {
    float lsum = 0.f;
#pragma unroll
    for (int r = 0; r < 4; ++r) {
      const float v = fmaxf(acc[ni][r], 1e-6f);
      const int grow = rowBase + wm + lq * 4 + r;
      const int gcol = ni * 16 + l15;
      t0[(size_t)grow * E_ + gcol] = __logf(v);
      lsum += v;
    }
    float v = lsum;
    v += __shfl_xor(v, 16);
    v += __shfl_xor(v, 32);
    if (lq == 0) atomicAdd(&slot0[b * E_ + ni * 16 + l15], v);
  }
}

// ---------------------------------------------------------------------------
// One Sinkhorn iteration (fused col+row pass):
//   C_it[e] = sum_j log(slots[j][b][e]); p = exp(t0 - C); s = row-sum(p);
//   last: out = p/s; else slots[it] += col-sum(p/s)
// ---------------------------------------------------------------------------
__global__ __launch_bounds__(256) void sinkhorn_iter(const float* __restrict__ t0,
                                                     float* __restrict__ slots,
                                                     float* __restrict__ out,
                                                     int it, int last) {
  const int tid = threadIdx.x;
  const int lane = tid & 63;
  const int wv = tid >> 6;
  const int b = blockIdx.x >> 8;
  const int chunk = blockIdx.x & 255;

  float C = __logf(slots[b * E_ + lane]);
  for (int j = 1; j < it; ++j) C += __logf(slots[j * (B_ * E_) + b * E_ + lane]);

  float colacc = 0.f;
  const int nbase = chunk * 32 + wv * 8;
#pragma unroll
  for (int i = 0; i < 8; ++i) {
    const int n = nbase + i;
    const float v = t0[((size_t)b * N_ + n) * E_ + lane];
    const float p = __expf(v - C);
    float s = p;
    s += __shfl_xor(s, 1);  s += __shfl_xor(s, 2);  s += __shfl_xor(s, 4);
    s += __shfl_xor(s, 8);  s += __shfl_xor(s, 16); s += __shfl_xor(s, 32);
    const float q = p / s;
    if (last) out[((size_t)b * N_ + n) * E_ + lane] = q;
    else      colacc += q;
  }
  if (!last) {
    __shared__ float wsum[4][64];
    wsum[wv][lane] = colacc;
    __syncthreads();
    if (tid < 64) {
      const float tot = wsum[0][tid] + wsum[1][tid] + wsum[2][tid] + wsum[3][tid];
      atomicAdd(&slots[it * (B_ * E_) + b * E_ + tid], tot);
    }
  }
}

// ---------------------------------------------------------------------------
extern "C" void kernel_launch(void* const* d_in, const int* in_sizes, int n_in,
                              void* d_out, int out_size, void* d_ws, size_t ws_size,
                              hipStream_t stream) {
  (void)in_sizes; (void)n_in; (void)out_size; (void)ws_size;
  const float* x = (const float*)d_in[0];
  const float* w = (const float*)d_in[1];
  float* out = (float*)d_out;                       // t0 lives here, final iter overwrites
  float* slots = (float*)d_ws;                      // [8][B_][E_] = 8 KiB
  _Float16* w16 = (_Float16*)((char*)d_ws + 8192);  // 512 KiB

  hipMemsetAsync(slots, 0, 8 * B_ * E_ * sizeof(float), stream);
  convert_w<<<(E_ * D_) / 1024, 256, 0, stream>>>(w, w16);
  gemm_log<<<M_ / 64, 256, 0, stream>>>(x, w16, out, slots);
  for (int it = 1; it <= 8; ++it)
    sinkhorn_iter<<<B_ * 256, 256, 0, stream>>>(out, slots, out, it, it == 8 ? 1 : 0);
}